// Round 5
// baseline (1068.922 us; speedup 1.0000x reference)
//
#include <hip/hip_runtime.h>
#include <stdint.h>

#define B_ 4
#define N_ 256
#define H_ 192
#define H3_ 576
#define F_ 64

// ---- workspace layout (32-bit words) ----
// HL/SL (MALL) and FHL/FSL (fast, XCD-L2) rows are 192 tagged u64:
// high32 = tag (t+1), low32 = fp32 bits. Tags 1..256; 0xAAAAAAAA poison never matches.
#define H0_OFF   0u
#define ZC_OFF   1024u
#define HL_OFF   2048u        // MALL h_prov rows [b][t][192] u64 (mirror-written)
#define SL_OFF   395264u      // MALL S rows (mirror-written)
#define AN_OFF   788480u      // [b][t][4] u64 ancestor masks
#define TG_OFF   796672u      // [b][t][4] u64 target masks
#define PL_OFF   804864u      // parent lists (u8)
#define PC_OFF   870400u      // parent counts
#define DG_OFF   871424u      // 1/deg
#define D_OFF    872448u      // d-history [b][blk][node][192] f32 (own-block cols of S[node]@W_ih)
#define G_OFF    1462272u     // G^T: [b][k][N]  (post-pass only)
#define C_OFF    1658880u     // Hprov@W1a + zc  (post-pass only)
#define FHL_OFF  1855488u     // fast (XCD-L2) h_prov rows
#define FSL_OFF  2248704u     // fast (XCD-L2) S rows
#define XC_OFF   2641920u     // [b][16] xcd-id exchange words

#define AN64 (AN_OFF/2)
#define TG64 (TG_OFF/2)

#define NF_OUT 262144u
#define LL_OUT 327680u

__device__ __forceinline__ float sigm_(float x){ return 1.0f/(1.0f + __expf(-x)); }
__device__ __forceinline__ float tanh_(float x){
  float ax = fabsf(x);
  float e = __expf(-2.0f*ax);
  float t = (1.0f - e)/(1.0f + e);
  return x < 0.0f ? -t : t;
}

// MALL (agent/sc1) tagged ops.
__device__ __forceinline__ void st_mall_(uint32_t* p, unsigned long long u){
  __hip_atomic_store((unsigned long long*)p, u, __ATOMIC_RELAXED, __HIP_MEMORY_SCOPE_AGENT);
}
__device__ __forceinline__ unsigned long long ld_mall_(const uint32_t* p){
  return __hip_atomic_load((const unsigned long long*)p, __ATOMIC_RELAXED, __HIP_MEMORY_SCOPE_AGENT);
}
// r1-proven fast-path load: invalidate L1 (sc0 level), then plain load -> XCD L2.
__device__ __forceinline__ unsigned long long ld_l2_(const uint32_t* p){
  unsigned long long v;
  asm volatile("buffer_inv sc0\n\t"
               "s_waitcnt vmcnt(0)\n\t"
               "global_load_dwordx2 %0, %1, off\n\t"
               "s_waitcnt vmcnt(0)"
               : "=v"(v) : "v"(p) : "memory");
  return v;
}
// fast-only publish: plain write-through store (own XCD L2). NO MALL store here —
// sc1 stores poison the wave's vmcnt (in-order retirement => any later vmcnt(0)
// waits the ~1000cy MALL ack). Mirror waves handle the MALL copy.
__device__ __forceinline__ void pubF_(uint32_t* fp, float v, uint32_t tag){
  unsigned long long u = ((unsigned long long)tag<<32) | (unsigned long long)__float_as_uint(v);
  __hip_atomic_store((unsigned long long*)fp, u, __ATOMIC_RELAXED, __HIP_MEMORY_SCOPE_WORKGROUP);
}
// dual publish (prologue only; drained once by a full __syncthreads).
__device__ __forceinline__ void pub2_(uint32_t* fp, uint32_t* mp, float v, uint32_t tag){
  unsigned long long u = ((unsigned long long)tag<<32) | (unsigned long long)__float_as_uint(v);
  __hip_atomic_store((unsigned long long*)fp, u, __ATOMIC_RELAXED, __HIP_MEMORY_SCOPE_WORKGROUP);
  st_mall_(mp, u);
}
// mirror: tag-spin on OWN block's fast row (same-CU plain loads, coherent) then
// copy the u64 to MALL. Depends only on own-block stores -> deadlock-free.
__device__ __forceinline__ void mirror_(const uint32_t* fp, uint32_t* mp, uint32_t tag){
  unsigned long long x;
  do {
    x = __hip_atomic_load((const unsigned long long*)fp, __ATOMIC_RELAXED, __HIP_MEMORY_SCOPE_WORKGROUP);
  } while ((uint32_t)(x>>32) != tag);
  st_mall_(mp, x);
}
// hang-proof hybrid poll: fast lanes spin on L2 copy, every 4th iter also accept the
// MALL copy (mirror-written); non-fast lanes spin on MALL only.
__device__ __forceinline__ float pollH_(const uint32_t* fp, const uint32_t* mp, int fast, uint32_t tag){
  unsigned long long x = 0; int it = 0;
  for(;;){
    if (fast){
      x = ld_l2_(fp);
      if ((uint32_t)(x>>32) != tag && (((++it) & 3) == 3)){
        unsigned long long m = ld_mall_(mp);
        if ((uint32_t)(m>>32) == tag) x = m;
      }
    } else {
      x = ld_mall_(mp);
    }
    if (__all((int)((uint32_t)(x>>32) == tag))) break;
  }
  return __uint_as_float((uint32_t)x);
}
// raw barrier: LDS ordering only — no vmcnt drain (the point of this round).
__device__ __forceinline__ void bar_(){
  asm volatile("s_waitcnt lgkmcnt(0)" ::: "memory");
  __builtin_amdgcn_s_barrier();
  asm volatile("" ::: "memory");
}

// ---------- pre1: (bx<N_): parent lists/bitmasks/deg | (bx==N_): h0, zc, ll=0 ----------
__global__ void __launch_bounds__(192) k_pre1(const float* __restrict__ z,
    const float* __restrict__ Winit, const float* __restrict__ binit,
    const float* __restrict__ W1, const float* __restrict__ b1,
    const float* __restrict__ tgt, float* ws, float* out)
{
  int bx = blockIdx.x, b = blockIdx.y, tid = threadIdx.x;
  if (bx == N_){
    __shared__ float zs[H_];
    zs[tid] = z[b*H_ + tid];
    __syncthreads();
    float a0=0.f, a1=0.f;
    for (int k=0;k<H_;k++){
      float zv = zs[k];
      a0 += zv * Winit[(size_t)k*H_ + tid];
      a1 += zv * W1[(size_t)(2*H_ + k)*H_ + tid];
    }
    ws[H0_OFF + b*H_ + tid] = tanh_(a0 + binit[tid]);
    ws[ZC_OFF + b*H_ + tid] = a1 + b1[tid];
    if (b==0 && tid==0) out[LL_OUT] = 0.0f;
    return;
  }
  if (tid >= 64) return;
  int t = bx, lane = tid;
  uint32_t* wsu = (uint32_t*)ws;
  unsigned long long* ws64 = (unsigned long long*)ws;
  const float* row = tgt + ((size_t)(b*N_) + t)*N_;
  uint8_t* pl = ((uint8_t*)&wsu[PL_OFF]) + (size_t)(b*N_ + t)*N_;
  int cnt = 0;
  #pragma unroll
  for (int m=0;m<4;m++){
    float v = row[m*64 + lane];
    bool p = (v != 0.0f);
    unsigned long long bw = __ballot(p);
    if (lane == 0) ws64[TG64 + (size_t)(b*N_+t)*4 + m] = bw;
    if (p){
      int pos = cnt + (int)__popcll(bw & ((1ULL<<lane)-1ULL));
      pl[pos] = (uint8_t)(m*64 + lane);
    }
    cnt += (int)__popcll(bw);
  }
  if (lane == 0){
    wsu[PC_OFF + b*N_ + t] = (uint32_t)cnt;
    ws[DG_OFF + b*N_ + t] = 1.0f / fmaxf((float)cnt, 1.0f);
  }
}

// ---------- pass 1: 3 blocks per batch, each owns 64 hidden elems (192 gate cols) ----------
// thread (e = tid>>3, kc = tid&7): owns cols {g*192 + blk*64 + e}, k-chunk [kc*24,kc*24+24).
// Roles: waves 0-1 (tid<128) poll foreign rows; wave 2 mirrors own FHL->HL (MALL) pre-B1;
// wave 3 mirrors own FSL->SL post-B1 (+ ancestor rows pre-B1 on blk0). Compute waves issue
// NO sc1 stores in the loop; in-loop barriers are raw s_barrier + lgkmcnt only — so no
// vmcnt(0) ever waits on a MALL ack on the critical path.
__global__ void __launch_bounds__(512, 1) k_pass1(const float* __restrict__ z,
    const float* __restrict__ Wih, const float* __restrict__ Whh,
    const float* __restrict__ bih_g, const float* __restrict__ bhh_g,
    float* ws)
{
  int bx = blockIdx.x;
  int b = bx & 7;
  if (b >= B_) return;
  int blk = bx >> 3;                 // 0..2, bx = b, 8+b, 16+b -> same XCD (round-robin)
  int tid = threadIdx.x;
  const int e  = tid >> 3;           // 0..63
  const int kc = tid & 7;            // 0..7
  const int E  = blk*64 + e;         // global hidden element

  float* wsf = ws;
  uint32_t* wsu = (uint32_t*)ws;
  unsigned long long* ws64 = (unsigned long long*)ws;

  __shared__ __align__(16) float sh[H_];     // h_prov(t), full vector
  __shared__ __align__(16) float ss[H_];     // S(t), full vector
  __shared__ float sDG[N_], sTF1[N_];
  __shared__ uint32_t sPC[N_];
  __shared__ int sfast[4];
  __shared__ unsigned long long sAB[N_][4];  // blk0 only

  // publish S(0) ASAP (tag 1, dual: peers haven't discovered XCDs yet)
  {
    float v = wsf[H0_OFF + b*H_ + E];
    if (kc == 0)
      pub2_(&wsu[FSL_OFF + (unsigned)(b*N_)*384u + 2u*(unsigned)E],
            &wsu[SL_OFF  + (unsigned)(b*N_)*384u + 2u*(unsigned)E], v, 1u);
    if (kc == 1) ss[E] = v;
  }

  // ---- XCD discovery + exchange (one-time; garbage-tolerant) ----
  uint32_t xcc = (uint32_t)__builtin_amdgcn_s_getreg((31u<<11) | 20u) & 15u;  // HW_REG_XCC_ID
  if (tid == 0)
    __hip_atomic_store(&wsu[XC_OFF + b*16 + blk], 0xC0DE0000u | xcc,
                       __ATOMIC_RELAXED, __HIP_MEMORY_SCOPE_AGENT);
  if (tid < 64){
    uint32_t v = 0; int ok;
    do {
      v = (tid < 3) ? __hip_atomic_load(&wsu[XC_OFF + b*16 + tid],
              __ATOMIC_RELAXED, __HIP_MEMORY_SCOPE_AGENT) : (0xC0DE0000u | xcc);
      ok = (int)((v >> 16) == 0xC0DEu);
    } while (!__all(ok));
    if (tid < 3) sfast[tid] = ((v & 0xFFu) == xcc) ? 1 : 0;
  }

  // ---- per-step scalar tables ----
  for (int i = tid; i < N_; i += 512){
    sDG[i] = wsf[DG_OFF + b*N_ + i];
    sPC[i] = wsu[PC_OFF + b*N_ + i];
    float f1 = 0.f;
    if (i >= 1){
      unsigned long long w1 = ws64[TG64 + (size_t)(b*N_+i)*4 + ((i-1)>>6)];
      f1 = (float)((w1 >> ((i-1)&63)) & 1ULL);
    }
    sTF1[i] = f1;
  }
  if (blk == 0 && tid >= 192 && tid < 196) sAB[0][tid-192] = 0ULL;

  // ---- weights: 3 gate cols x 24-k chunk ----
  float rwih[3][24], rwhh[3][24], rbih[3], rbhh[3], rghz[3];
  #pragma unroll
  for (int g=0; g<3; g++){
    int col = g*H_ + E;
    #pragma unroll
    for (int i=0;i<24;i++){
      rwih[g][i] = Wih[(size_t)(kc*24+i)*H3_ + col];
      rwhh[g][i] = Whh[(size_t)(kc*24+i)*H3_ + col];
    }
    rbih[g] = bih_g[col];
    rbhh[g] = bhh_g[col];
  }
  {
    // ghz = z@W_hh + b_hh (const across steps)
    float a0=0.f,a1=0.f,a2=0.f;
    #pragma unroll
    for (int i=0;i<24;i++){
      float zv = z[b*H_ + kc*24 + i];
      a0 += zv*rwhh[0][i]; a1 += zv*rwhh[1][i]; a2 += zv*rwhh[2][i];
    }
    #pragma unroll
    for (int m=1;m<8;m<<=1){
      a0 += __shfl_xor(a0,m); a1 += __shfl_xor(a1,m); a2 += __shfl_xor(a2,m);
    }
    rghz[0]=a0+rbhh[0]; rghz[1]=a1+rbhh[1]; rghz[2]=a2+rbhh[2];
  }
  float zreg = z[b*H_ + E];

  __syncthreads();   // full drain: S(0) dual-publish committed
  // poll foreign S(0) into LDS
  if (tid < 128){
    int j = (tid < blk*64) ? tid : tid + 64;
    ss[j] = pollH_(&wsu[FSL_OFF + (unsigned)(b*N_)*384u + 2u*(unsigned)j],
                   &wsu[SL_OFF  + (unsigned)(b*N_)*384u + 2u*(unsigned)j],
                   sfast[j>>6], 1u);
  }
  __syncthreads();

  float q0=0.f, q1=0.f, q2=0.f;
  const uint8_t* plbase = ((const uint8_t*)&wsu[PL_OFF]) + (size_t)(b*N_)*N_;
  float* Dbase = wsf + D_OFF + (size_t)((b*3+blk)*N_)*H_;

  for (int t=1; t<N_; t++){
    const uint32_t tagH = (uint32_t)(t+1);
    // ---- mv1: d = S(t-1) @ W_ih (own 3 cols, k-chunk), butterfly over kc ----
    float d0=0.f,d1=0.f,d2=0.f;
    #pragma unroll
    for (int c=0;c<6;c++){
      float4 v4 = *(const float4*)&ss[kc*24 + c*4];
      float xx0=v4.x, xx1=v4.y, xx2=v4.z, xx3=v4.w;
      d0 += xx0*rwih[0][c*4+0]; d1 += xx0*rwih[1][c*4+0]; d2 += xx0*rwih[2][c*4+0];
      d0 += xx1*rwih[0][c*4+1]; d1 += xx1*rwih[1][c*4+1]; d2 += xx1*rwih[2][c*4+1];
      d0 += xx2*rwih[0][c*4+2]; d1 += xx2*rwih[1][c*4+2]; d2 += xx2*rwih[2][c*4+2];
      d0 += xx3*rwih[0][c*4+3]; d1 += xx3*rwih[1][c*4+3]; d2 += xx3*rwih[2][c*4+3];
    }
    #pragma unroll
    for (int m=1;m<8;m<<=1){
      d0 += __shfl_xor(d0,m); d1 += __shfl_xor(d1,m); d2 += __shfl_xor(d2,m);
    }
    q0 += d0; q1 += d1; q2 += d2;
    float invt = 1.0f/(float)t;
    // ---- gates1: h_prov ----
    float r = sigm_(q0*invt + rbih[0] + rghz[0]);
    float u = sigm_(q1*invt + rbih[1] + rghz[1]);
    float n = tanh_(q2*invt + rbih[2] + r*rghz[2]);
    float hp = (1.0f-u)*n + u*zreg;
    // publish h_prov (fast only) + store own d row (node t-1)
    if (kc == 0){
      pubF_(&wsu[FHL_OFF + (unsigned)(b*N_+t)*384u + 2u*(unsigned)E], hp, tagH);
      float* Dr = Dbase + (size_t)(t-1)*H_;
      Dr[e] = d0; Dr[64+e] = d1; Dr[128+e] = d2;
    }
    if (kc == 1) sh[E] = hp;
    // ---- gather parent d (p <= t-2; p==t-1 handled via tf1*d in-reg) ----
    // the gather-use vmcnt(0) below also guarantees this step's D stores committed.
    float ga0=0.f, ga1=0.f, ga2=0.f;
    {
      int pc = (int)sPC[t];
      const uint8_t* pl = plbase + (size_t)t*N_;
      for (int i=kc; i<pc; i+=8){
        int p = pl[i];
        if (p == t-1) continue;
        const float* Dp = Dbase + (size_t)p*H_;
        ga0 += Dp[e]; ga1 += Dp[64+e]; ga2 += Dp[128+e];
      }
    }
    #pragma unroll
    for (int m=1;m<8;m<<=1){
      ga0 += __shfl_xor(ga0,m); ga1 += __shfl_xor(ga1,m); ga2 += __shfl_xor(ga2,m);
    }
    // ---- phase-1: pollers / h-mirror / ancestor ----
    if (tid < 128){
      int j = (tid < blk*64) ? tid : tid + 64;
      sh[j] = pollH_(&wsu[FHL_OFF + (unsigned)(b*N_+t)*384u + 2u*(unsigned)j],
                     &wsu[HL_OFF  + (unsigned)(b*N_+t)*384u + 2u*(unsigned)j],
                     sfast[j>>6], tagH);
    } else if (tid < 192){
      int ml = tid - 128;                     // wave 2: MALL mirror of own h row
      unsigned em = (unsigned)(blk*64 + ml);
      mirror_(&wsu[FHL_OFF + (unsigned)(b*N_+t)*384u + 2u*em],
              &wsu[HL_OFF  + (unsigned)(b*N_+t)*384u + 2u*em], tagH);
    } else if (blk == 0 && tid < 208){
      int lane16 = tid - 192;                 // wave 3 (blk0): ancestor row t
      int ip = lane16 >> 2, w = lane16 & 3;
      int pc = (int)sPC[t];
      const uint8_t* pl = plbase + (size_t)t*N_;
      unsigned long long acc = 0ULL;
      for (int i=ip; i<pc; i+=4) acc |= sAB[pl[i]][w];
      acc |= __shfl_xor(acc, 4);
      acc |= __shfl_xor(acc, 8);
      if (ip == 0){
        ws64[AN64 + (size_t)(b*N_+t)*4 + w] = acc;
        sAB[t][w] = acc | ws64[TG64 + (size_t)(b*N_+t)*4 + w];
      }
    }
    bar_();   // B1 (lgkm only)
    // ---- mv2: gh2 = h_prov @ W_hh ----
    float y0=0.f,y1=0.f,y2=0.f;
    #pragma unroll
    for (int c=0;c<6;c++){
      float4 v4 = *(const float4*)&sh[kc*24 + c*4];
      float xx0=v4.x, xx1=v4.y, xx2=v4.z, xx3=v4.w;
      y0 += xx0*rwhh[0][c*4+0]; y1 += xx0*rwhh[1][c*4+0]; y2 += xx0*rwhh[2][c*4+0];
      y0 += xx1*rwhh[0][c*4+1]; y1 += xx1*rwhh[1][c*4+1]; y2 += xx1*rwhh[2][c*4+1];
      y0 += xx2*rwhh[0][c*4+2]; y1 += xx2*rwhh[1][c*4+2]; y2 += xx2*rwhh[2][c*4+2];
      y0 += xx3*rwhh[0][c*4+3]; y1 += xx3*rwhh[1][c*4+3]; y2 += xx3*rwhh[2][c*4+3];
    }
    #pragma unroll
    for (int m=1;m<8;m<<=1){
      y0 += __shfl_xor(y0,m); y1 += __shfl_xor(y1,m); y2 += __shfl_xor(y2,m);
    }
    // ---- gates2: S(t) ----
    float dginv = sDG[t], tf1 = sTF1[t];
    float gxa = (ga0 + tf1*d0)*dginv + rbih[0];
    float gxb = (ga1 + tf1*d1)*dginv + rbih[1];
    float gxc = (ga2 + tf1*d2)*dginv + rbih[2];
    float r2 = sigm_(gxa + y0 + rbhh[0]);
    float u2 = sigm_(gxb + y1 + rbhh[1]);
    float n2 = tanh_(gxc + r2*(y2 + rbhh[2]));
    float hn = (1.0f-u2)*n2 + u2*hp;
    if (kc == 0)
      pubF_(&wsu[FSL_OFF + (unsigned)(b*N_+t)*384u + 2u*(unsigned)E], hn, tagH);
    if (kc == 1) ss[E] = hn;
    // ---- phase-2: pollers / S-mirror ----
    if (tid < 128){
      int j = (tid < blk*64) ? tid : tid + 64;
      ss[j] = pollH_(&wsu[FSL_OFF + (unsigned)(b*N_+t)*384u + 2u*(unsigned)j],
                     &wsu[SL_OFF  + (unsigned)(b*N_+t)*384u + 2u*(unsigned)j],
                     sfast[j>>6], tagH);
    } else if (tid >= 192 && tid < 256){
      int ml = tid - 192;                     // wave 3: MALL mirror of own S row
      unsigned em = (unsigned)(blk*64 + ml);
      mirror_(&wsu[FSL_OFF + (unsigned)(b*N_+t)*384u + 2u*em],
              &wsu[SL_OFF  + (unsigned)(b*N_+t)*384u + 2u*em], tagH);
    }
    bar_();   // B2 (lgkm only)
  }
}

// ---------- pass 2a: G^T = (S@W1b)^T, C = Hprov@W1a + zc, NF = S@Wf + bf ----------
// reads the MALL (SL/HL) copies — mirror-written for all t; kernel boundary = acquire.
__global__ void k_p2a(const float* __restrict__ W1, const float* __restrict__ Wf,
    const float* __restrict__ bf, float* ws, float* out)
{
  int j = blockIdx.x, b = blockIdx.y, tid = threadIdx.x;
  __shared__ float srow[H_], hrow[H_];
  __shared__ float nfp[3][F_];
  srow[tid] = ws[SL_OFF + (unsigned)(b*N_+j)*384u + 2u*tid];
  hrow[tid] = ws[HL_OFF + (unsigned)(b*N_+j)*384u + 2u*tid];   // garbage for j=0, C[0] unused
  __syncthreads();
  float accG = 0.f, accC = 0.f;
  for (int k=0;k<H_;k++){
    float sv = srow[k], hv = hrow[k];
    accG += sv * W1[(size_t)(H_+k)*H_ + tid];
    accC += hv * W1[(size_t)k*H_ + tid];
  }
  ws[G_OFF + ((size_t)b*H_ + tid)*N_ + j] = accG;    // transposed store
  ws[C_OFF + (size_t)(b*N_+j)*H_ + tid] = accC + ws[ZC_OFF + b*H_ + tid];
  int f = tid & 63, kp = tid >> 6;
  float a = 0.f;
  for (int i=0;i<64;i++){ int k = kp*64 + i; a += srow[k]*Wf[(size_t)k*F_ + f]; }
  nfp[kp][f] = a;
  __syncthreads();
  if (tid < F_) out[NF_OUT + (size_t)(b*N_+j)*F_ + tid] = nfp[0][tid]+nfp[1][tid]+nfp[2][tid] + bf[tid];
}

// ---------- pass 2b: log-likelihood, lane-per-candidate-parent ----------
__global__ void __launch_bounds__(256) k_p2b(const float* __restrict__ W2,
    const float* __restrict__ b2p, float* ws, float* out)
{
  int t = blockIdx.x + 1, b = blockIdx.y;
  int tid = threadIdx.x; int lane = tid & 63; int wv = tid >> 6;
  __shared__ float cv[H_], w2s[H_];
  __shared__ float wsum[4];
  unsigned long long* ws64 = (unsigned long long*)ws;
  if (tid < H_){
    cv[tid] = ws[C_OFF + (size_t)(b*N_+t)*H_ + tid];
    w2s[tid] = W2[tid];
  }
  __syncthreads();
  float acc = 0.f;
  if (tid < t){
    const float* GT = ws + G_OFF + (size_t)b*H_*N_;
    float a = 0.f;
    for (int k=0;k<H_;k++) a += fmaxf(cv[k] + GT[(size_t)k*N_ + tid], 0.f) * w2s[k];
    float logit = a + b2p[0];
    float pp = 1.0f/(1.0f+__expf(-logit));
    unsigned long long an = ws64[AN64 + (size_t)(b*N_+t)*4 + (tid>>6)];
    unsigned long long tg = ws64[TG64 + (size_t)(b*N_+t)*4 + (tid>>6)];
    float anc = (float)((an >> (tid&63)) & 1ULL);
    pp = pp * (1.0f - anc);
    pp = fminf(fmaxf(pp, 1e-6f), 1.0f - 1e-6f);
    int tgb = (int)((tg >> (tid&63)) & 1ULL);
    acc = tgb ? logf(pp) : log1pf(-pp);
  }
  #pragma unroll
  for (int m=32;m>=1;m>>=1) acc += __shfl_xor(acc, m);
  if (lane == 0) wsum[wv] = acc;
  __syncthreads();
  if (tid == 0) atomicAdd(out + LL_OUT, wsum[0]+wsum[1]+wsum[2]+wsum[3]);
}

extern "C" void kernel_launch(void* const* d_in, const int* in_sizes, int n_in,
                              void* d_out, int out_size, void* d_ws, size_t ws_size,
                              hipStream_t stream) {
  (void)in_sizes; (void)n_in; (void)out_size; (void)ws_size;
  const float* z     = (const float*)d_in[0];
  const float* tgt   = (const float*)d_in[1];
  const float* Winit = (const float*)d_in[2];
  const float* binit = (const float*)d_in[3];
  const float* Wih   = (const float*)d_in[4];
  const float* Whh   = (const float*)d_in[5];
  const float* bih   = (const float*)d_in[6];
  const float* bhh   = (const float*)d_in[7];
  const float* W1    = (const float*)d_in[8];
  const float* b1    = (const float*)d_in[9];
  const float* W2    = (const float*)d_in[10];
  const float* b2    = (const float*)d_in[11];
  const float* Wf    = (const float*)d_in[12];
  const float* bf    = (const float*)d_in[13];
  float* out = (float*)d_out;
  float* ws  = (float*)d_ws;

  hipMemcpyAsync(d_out, d_in[1], (size_t)B_*N_*N_*sizeof(float), hipMemcpyDeviceToDevice, stream);

  k_pre1<<<dim3(N_+1, B_), dim3(192), 0, stream>>>(z, Winit, binit, W1, b1, tgt, ws, out);
  k_pass1<<<dim3(24), dim3(512), 0, stream>>>(z, Wih, Whh, bih, bhh, ws);
  k_p2a<<<dim3(N_, B_), dim3(H_), 0, stream>>>(W1, Wf, bf, ws, out);
  k_p2b<<<dim3(N_-1, B_), dim3(256), 0, stream>>>(W2, b2, ws, out);
}

// Round 6
// 1013.084 us; speedup vs baseline: 1.0551x; 1.0551x over previous
//
#include <hip/hip_runtime.h>
#include <stdint.h>

#define B_ 4
#define N_ 256
#define H_ 192
#define H3_ 576
#define F_ 64

// ---- workspace layout (32-bit words) ----
// HL/SL (MALL) and FHL/FSL (fast, XCD-L2) rows are 192 tagged u64:
// high32 = tag (t+1), low32 = fp32 bits. Tags 1..256; 0xAAAAAAAA poison never matches.
#define H0_OFF   0u
#define ZC_OFF   1024u
#define HL_OFF   2048u        // MALL h_prov rows [b][t][192] u64 (wave-3 written)
#define SL_OFF   395264u      // MALL S rows (wave-3 written)
#define AN_OFF   788480u      // [b][t][4] u64 ancestor masks
#define TG_OFF   796672u      // [b][t][4] u64 target masks
#define PL_OFF   804864u      // parent lists (u8)
#define PC_OFF   870400u      // parent counts
#define DG_OFF   871424u      // 1/deg
#define D_OFF    872448u      // d-history [b][blk][node][192] f32 (own-block cols of S[node]@W_ih)
#define G_OFF    1462272u     // G^T: [b][k][N]  (post-pass only)
#define C_OFF    1658880u     // Hprov@W1a + zc  (post-pass only)
#define FHL_OFF  1855488u     // fast (XCD-L2) h_prov rows
#define FSL_OFF  2248704u     // fast (XCD-L2) S rows
#define XC_OFF   2641920u     // [b][16] xcd-id exchange words

#define AN64 (AN_OFF/2)
#define TG64 (TG_OFF/2)

#define NF_OUT 262144u
#define LL_OUT 327680u

__device__ __forceinline__ float sigm_(float x){ return 1.0f/(1.0f + __expf(-x)); }
__device__ __forceinline__ float tanh_(float x){
  float ax = fabsf(x);
  float e = __expf(-2.0f*ax);
  float t = (1.0f - e)/(1.0f + e);
  return x < 0.0f ? -t : t;
}

// MALL (agent/sc1) tagged ops.
__device__ __forceinline__ void st_mall_(uint32_t* p, unsigned long long u){
  __hip_atomic_store((unsigned long long*)p, u, __ATOMIC_RELAXED, __HIP_MEMORY_SCOPE_AGENT);
}
__device__ __forceinline__ unsigned long long ld_mall_(const uint32_t* p){
  return __hip_atomic_load((const unsigned long long*)p, __ATOMIC_RELAXED, __HIP_MEMORY_SCOPE_AGENT);
}
// fast-path poll load: NT (non-temporal) = no L1 allocate. FHL/FSL lines are never
// load-allocated by anything else and stores are no-write-allocate, so an nt load
// always reads the XCD-shared L2 (~300cy round trip) — no buffer_inv, no L1 nuking.
// (r2 proved plain/sc0 spins hit own stale L1; r1's buffer_inv works but ~1kcy/iter.)
__device__ __forceinline__ unsigned long long ld_l2_(const uint32_t* p){
  unsigned long long v;
  asm volatile("global_load_dwordx2 %0, %1, off nt\n\t"
               "s_waitcnt vmcnt(0)"
               : "=v"(v) : "v"(p) : "memory");
  return v;
}
// fast-only publish: plain write-through store (own XCD L2), cheap ack.
__device__ __forceinline__ void pubF_(uint32_t* fp, float v, uint32_t tag){
  unsigned long long u = ((unsigned long long)tag<<32) | (unsigned long long)__float_as_uint(v);
  __hip_atomic_store((unsigned long long*)fp, u, __ATOMIC_RELAXED, __HIP_MEMORY_SCOPE_WORKGROUP);
}
// dual publish (prologue only; drained once by a full __syncthreads).
__device__ __forceinline__ void pub2_(uint32_t* fp, uint32_t* mp, float v, uint32_t tag){
  unsigned long long u = ((unsigned long long)tag<<32) | (unsigned long long)__float_as_uint(v);
  __hip_atomic_store((unsigned long long*)fp, u, __ATOMIC_RELAXED, __HIP_MEMORY_SCOPE_WORKGROUP);
  st_mall_(mp, u);
}
// hang-proof hybrid poll: fast lanes spin on L2 (nt) copy, every 4th iter also accept
// the MALL copy (wave-3 written); non-fast lanes spin on MALL only.
__device__ __forceinline__ float pollH_(const uint32_t* fp, const uint32_t* mp, int fast, uint32_t tag){
  unsigned long long x = 0; int it = 0;
  for(;;){
    if (fast){
      x = ld_l2_(fp);
      if ((uint32_t)(x>>32) != tag && (((++it) & 3) == 3)){
        unsigned long long m = ld_mall_(mp);
        if ((uint32_t)(m>>32) == tag) x = m;
      }
    } else {
      x = ld_mall_(mp);
    }
    if (__all((int)((uint32_t)(x>>32) == tag))) break;
  }
  return __uint_as_float((uint32_t)x);
}
// raw barrier: LDS ordering only — never drains vmcnt (keeps MALL/store acks off
// the critical path).
__device__ __forceinline__ void bar_(){
  asm volatile("s_waitcnt lgkmcnt(0)" ::: "memory");
  __builtin_amdgcn_s_barrier();
  asm volatile("" ::: "memory");
}

// ---------- pre1: (bx<N_): parent lists/bitmasks/deg | (bx==N_): h0, zc, ll=0 ----------
__global__ void __launch_bounds__(192) k_pre1(const float* __restrict__ z,
    const float* __restrict__ Winit, const float* __restrict__ binit,
    const float* __restrict__ W1, const float* __restrict__ b1,
    const float* __restrict__ tgt, float* ws, float* out)
{
  int bx = blockIdx.x, b = blockIdx.y, tid = threadIdx.x;
  if (bx == N_){
    __shared__ float zs[H_];
    zs[tid] = z[b*H_ + tid];
    __syncthreads();
    float a0=0.f, a1=0.f;
    for (int k=0;k<H_;k++){
      float zv = zs[k];
      a0 += zv * Winit[(size_t)k*H_ + tid];
      a1 += zv * W1[(size_t)(2*H_ + k)*H_ + tid];
    }
    ws[H0_OFF + b*H_ + tid] = tanh_(a0 + binit[tid]);
    ws[ZC_OFF + b*H_ + tid] = a1 + b1[tid];
    if (b==0 && tid==0) out[LL_OUT] = 0.0f;
    return;
  }
  if (tid >= 64) return;
  int t = bx, lane = tid;
  uint32_t* wsu = (uint32_t*)ws;
  unsigned long long* ws64 = (unsigned long long*)ws;
  const float* row = tgt + ((size_t)(b*N_) + t)*N_;
  uint8_t* pl = ((uint8_t*)&wsu[PL_OFF]) + (size_t)(b*N_ + t)*N_;
  int cnt = 0;
  #pragma unroll
  for (int m=0;m<4;m++){
    float v = row[m*64 + lane];
    bool p = (v != 0.0f);
    unsigned long long bw = __ballot(p);
    if (lane == 0) ws64[TG64 + (size_t)(b*N_+t)*4 + m] = bw;
    if (p){
      int pos = cnt + (int)__popcll(bw & ((1ULL<<lane)-1ULL));
      pl[pos] = (uint8_t)(m*64 + lane);
    }
    cnt += (int)__popcll(bw);
  }
  if (lane == 0){
    wsu[PC_OFF + b*N_ + t] = (uint32_t)cnt;
    ws[DG_OFF + b*N_ + t] = 1.0f / fmaxf((float)cnt, 1.0f);
  }
}

// ---------- pass 1: 3 blocks per batch, each owns 64 hidden elems (192 gate cols) ----------
// thread (e = tid>>3, kc = tid&7): owns cols {g*192 + blk*64 + e}, k-chunk [kc*24,kc*24+24).
// Per step, 4 raw (lgkm-only) barriers split each exchange into:
//   compute -> LDS route -> Ba -> {wv2: fast publish; wv0-1: gather+nt-poll; wv3:
//   gather then MALL publish; wv4: ancestors (blk0)} -> Bb -> next compute.
// No wave ever waits vmcnt on a MALL ack; poll iterations are single nt L2 loads.
__global__ void __launch_bounds__(512, 1) k_pass1(const float* __restrict__ z,
    const float* __restrict__ Wih, const float* __restrict__ Whh,
    const float* __restrict__ bih_g, const float* __restrict__ bhh_g,
    float* ws)
{
  int bx = blockIdx.x;
  int b = bx & 7;
  if (b >= B_) return;
  int blk = bx >> 3;                 // 0..2, bx = b, 8+b, 16+b
  int tid = threadIdx.x;
  const int e  = tid >> 3;           // 0..63
  const int kc = tid & 7;            // 0..7
  const int E  = blk*64 + e;         // global hidden element
  const int wv = tid >> 6;           // wave id 0..7
  const int l6 = tid & 63;

  float* wsf = ws;
  uint32_t* wsu = (uint32_t*)ws;
  unsigned long long* ws64 = (unsigned long long*)ws;

  __shared__ __align__(16) float sh[H_];     // h_prov(t), full vector
  __shared__ __align__(16) float ss[H_];     // S(t), full vector
  __shared__ float sDG[N_], sTF1[N_];
  __shared__ uint32_t sPC[N_];
  __shared__ int sfast[4];
  __shared__ unsigned long long sAB[N_][4];  // blk0 only

  // publish S(0) ASAP (tag 1, dual: peers haven't discovered XCDs yet)
  {
    float v = wsf[H0_OFF + b*H_ + E];
    if (kc == 0)
      pub2_(&wsu[FSL_OFF + (unsigned)(b*N_)*384u + 2u*(unsigned)E],
            &wsu[SL_OFF  + (unsigned)(b*N_)*384u + 2u*(unsigned)E], v, 1u);
    if (kc == 1) ss[E] = v;
  }

  // ---- XCD discovery + exchange (one-time; garbage-tolerant) ----
  uint32_t xcc = (uint32_t)__builtin_amdgcn_s_getreg((31u<<11) | 20u) & 15u;  // HW_REG_XCC_ID
  if (tid == 0)
    __hip_atomic_store(&wsu[XC_OFF + b*16 + blk], 0xC0DE0000u | xcc,
                       __ATOMIC_RELAXED, __HIP_MEMORY_SCOPE_AGENT);
  if (tid < 64){
    uint32_t v = 0; int ok;
    do {
      v = (tid < 3) ? __hip_atomic_load(&wsu[XC_OFF + b*16 + tid],
              __ATOMIC_RELAXED, __HIP_MEMORY_SCOPE_AGENT) : (0xC0DE0000u | xcc);
      ok = (int)((v >> 16) == 0xC0DEu);
    } while (!__all(ok));
    if (tid < 3) sfast[tid] = ((v & 0xFFu) == xcc) ? 1 : 0;
  }

  // ---- per-step scalar tables ----
  for (int i = tid; i < N_; i += 512){
    sDG[i] = wsf[DG_OFF + b*N_ + i];
    sPC[i] = wsu[PC_OFF + b*N_ + i];
    float f1 = 0.f;
    if (i >= 1){
      unsigned long long w1 = ws64[TG64 + (size_t)(b*N_+i)*4 + ((i-1)>>6)];
      f1 = (float)((w1 >> ((i-1)&63)) & 1ULL);
    }
    sTF1[i] = f1;
  }
  if (blk == 0 && tid >= 192 && tid < 196) sAB[0][tid-192] = 0ULL;

  // ---- weights: 3 gate cols x 24-k chunk ----
  float rwih[3][24], rwhh[3][24], rbih[3], rbhh[3], rghz[3];
  #pragma unroll
  for (int g=0; g<3; g++){
    int col = g*H_ + E;
    #pragma unroll
    for (int i=0;i<24;i++){
      rwih[g][i] = Wih[(size_t)(kc*24+i)*H3_ + col];
      rwhh[g][i] = Whh[(size_t)(kc*24+i)*H3_ + col];
    }
    rbih[g] = bih_g[col];
    rbhh[g] = bhh_g[col];
  }
  {
    // ghz = z@W_hh + b_hh (const across steps)
    float a0=0.f,a1=0.f,a2=0.f;
    #pragma unroll
    for (int i=0;i<24;i++){
      float zv = z[b*H_ + kc*24 + i];
      a0 += zv*rwhh[0][i]; a1 += zv*rwhh[1][i]; a2 += zv*rwhh[2][i];
    }
    #pragma unroll
    for (int m=1;m<8;m<<=1){
      a0 += __shfl_xor(a0,m); a1 += __shfl_xor(a1,m); a2 += __shfl_xor(a2,m);
    }
    rghz[0]=a0+rbhh[0]; rghz[1]=a1+rbhh[1]; rghz[2]=a2+rbhh[2];
  }
  float zreg = z[b*H_ + E];

  __syncthreads();   // full drain: S(0) dual-publish committed
  // poll foreign S(0) into LDS
  if (tid < 128){
    int j = (tid < blk*64) ? tid : tid + 64;
    ss[j] = pollH_(&wsu[FSL_OFF + (unsigned)(b*N_)*384u + 2u*(unsigned)j],
                   &wsu[SL_OFF  + (unsigned)(b*N_)*384u + 2u*(unsigned)j],
                   sfast[j>>6], 1u);
  }
  __syncthreads();

  float q0=0.f, q1=0.f, q2=0.f;
  const uint8_t* plbase = ((const uint8_t*)&wsu[PL_OFF]) + (size_t)(b*N_)*N_;
  float* Dbase = wsf + D_OFF + (size_t)((b*3+blk)*N_)*H_;

  for (int t=1; t<N_; t++){
    const uint32_t tagH = (uint32_t)(t+1);
    // ---- mv1: d = S(t-1) @ W_ih (own 3 cols, k-chunk), butterfly over kc ----
    float d0=0.f,d1=0.f,d2=0.f;
    #pragma unroll
    for (int c=0;c<6;c++){
      float4 v4 = *(const float4*)&ss[kc*24 + c*4];
      float xx0=v4.x, xx1=v4.y, xx2=v4.z, xx3=v4.w;
      d0 += xx0*rwih[0][c*4+0]; d1 += xx0*rwih[1][c*4+0]; d2 += xx0*rwih[2][c*4+0];
      d0 += xx1*rwih[0][c*4+1]; d1 += xx1*rwih[1][c*4+1]; d2 += xx1*rwih[2][c*4+1];
      d0 += xx2*rwih[0][c*4+2]; d1 += xx2*rwih[1][c*4+2]; d2 += xx2*rwih[2][c*4+2];
      d0 += xx3*rwih[0][c*4+3]; d1 += xx3*rwih[1][c*4+3]; d2 += xx3*rwih[2][c*4+3];
    }
    #pragma unroll
    for (int m=1;m<8;m<<=1){
      d0 += __shfl_xor(d0,m); d1 += __shfl_xor(d1,m); d2 += __shfl_xor(d2,m);
    }
    q0 += d0; q1 += d1; q2 += d2;
    float invt = 1.0f/(float)t;
    // ---- gates1: h_prov ----
    float r = sigm_(q0*invt + rbih[0] + rghz[0]);
    float u = sigm_(q1*invt + rbih[1] + rghz[1]);
    float n = tanh_(q2*invt + rbih[2] + r*rghz[2]);
    float hp = (1.0f-u)*n + u*zreg;
    // route h_prov to LDS + store own d row (node t-1)
    if (kc == 0){
      float* Dr = Dbase + (size_t)(t-1)*H_;
      Dr[e] = d0; Dr[64+e] = d1; Dr[128+e] = d2;
    }
    if (kc == 1) sh[E] = hp;
    bar_();   // B1a — sh[own] complete
    // wave 2: fast publish own h row from LDS (peers' nt-polls see this)
    if (wv == 2){
      unsigned em = (unsigned)(blk*64 + l6);
      pubF_(&wsu[FHL_OFF + (unsigned)(b*N_+t)*384u + 2u*em], sh[em], tagH);
    }
    // ---- gather parent d (all waves; p==t-1 handled via tf1*d in-reg) ----
    float ga0=0.f, ga1=0.f, ga2=0.f;
    {
      int pc = (int)sPC[t];
      const uint8_t* pl = plbase + (size_t)t*N_;
      for (int i=kc; i<pc; i+=8){
        int p = pl[i];
        if (p == t-1) continue;
        const float* Dp = Dbase + (size_t)p*H_;
        ga0 += Dp[e]; ga1 += Dp[64+e]; ga2 += Dp[128+e];
      }
    }
    #pragma unroll
    for (int m=1;m<8;m<<=1){
      ga0 += __shfl_xor(ga0,m); ga1 += __shfl_xor(ga1,m); ga2 += __shfl_xor(ga2,m);
    }
    // wave 3: MALL publish (after gather so its vmcnt(0) never waits MALL acks)
    if (wv == 3){
      unsigned em = (unsigned)(blk*64 + l6);
      unsigned long long u64v = ((unsigned long long)tagH<<32) |
                                (unsigned long long)__float_as_uint(sh[em]);
      st_mall_(&wsu[HL_OFF + (unsigned)(b*N_+t)*384u + 2u*em], u64v);
    }
    // waves 0-1: poll foreign h; wave 4 (blk0): ancestor row t
    if (tid < 128){
      int j = (tid < blk*64) ? tid : tid + 64;
      sh[j] = pollH_(&wsu[FHL_OFF + (unsigned)(b*N_+t)*384u + 2u*(unsigned)j],
                     &wsu[HL_OFF  + (unsigned)(b*N_+t)*384u + 2u*(unsigned)j],
                     sfast[j>>6], tagH);
    } else if (blk == 0 && wv == 4 && l6 < 16){
      int ip = l6 >> 2, w = l6 & 3;
      int pc = (int)sPC[t];
      const uint8_t* pl = plbase + (size_t)t*N_;
      unsigned long long acc = 0ULL;
      for (int i=ip; i<pc; i+=4) acc |= sAB[pl[i]][w];
      acc |= __shfl_xor(acc, 4);
      acc |= __shfl_xor(acc, 8);
      if (ip == 0){
        ws64[AN64 + (size_t)(b*N_+t)*4 + w] = acc;
        sAB[t][w] = acc | ws64[TG64 + (size_t)(b*N_+t)*4 + w];
      }
    }
    bar_();   // B1b — sh full
    // ---- mv2: gh2 = h_prov @ W_hh ----
    float y0=0.f,y1=0.f,y2=0.f;
    #pragma unroll
    for (int c=0;c<6;c++){
      float4 v4 = *(const float4*)&sh[kc*24 + c*4];
      float xx0=v4.x, xx1=v4.y, xx2=v4.z, xx3=v4.w;
      y0 += xx0*rwhh[0][c*4+0]; y1 += xx0*rwhh[1][c*4+0]; y2 += xx0*rwhh[2][c*4+0];
      y0 += xx1*rwhh[0][c*4+1]; y1 += xx1*rwhh[1][c*4+1]; y2 += xx1*rwhh[2][c*4+1];
      y0 += xx2*rwhh[0][c*4+2]; y1 += xx2*rwhh[1][c*4+2]; y2 += xx2*rwhh[2][c*4+2];
      y0 += xx3*rwhh[0][c*4+3]; y1 += xx3*rwhh[1][c*4+3]; y2 += xx3*rwhh[2][c*4+3];
    }
    #pragma unroll
    for (int m=1;m<8;m<<=1){
      y0 += __shfl_xor(y0,m); y1 += __shfl_xor(y1,m); y2 += __shfl_xor(y2,m);
    }
    // ---- gates2: S(t) ----
    float dginv = sDG[t], tf1 = sTF1[t];
    float gxa = (ga0 + tf1*d0)*dginv + rbih[0];
    float gxb = (ga1 + tf1*d1)*dginv + rbih[1];
    float gxc = (ga2 + tf1*d2)*dginv + rbih[2];
    float r2 = sigm_(gxa + y0 + rbhh[0]);
    float u2 = sigm_(gxb + y1 + rbhh[1]);
    float n2 = tanh_(gxc + r2*(y2 + rbhh[2]));
    float hn = (1.0f-u2)*n2 + u2*hp;
    if (kc == 1) ss[E] = hn;
    bar_();   // B2a — ss[own] complete
    if (wv == 2){
      unsigned em = (unsigned)(blk*64 + l6);
      pubF_(&wsu[FSL_OFF + (unsigned)(b*N_+t)*384u + 2u*em], ss[em], tagH);
    } else if (wv == 3){
      unsigned em = (unsigned)(blk*64 + l6);
      unsigned long long u64v = ((unsigned long long)tagH<<32) |
                                (unsigned long long)__float_as_uint(ss[em]);
      st_mall_(&wsu[SL_OFF + (unsigned)(b*N_+t)*384u + 2u*em], u64v);
    }
    if (tid < 128){
      int j = (tid < blk*64) ? tid : tid + 64;
      ss[j] = pollH_(&wsu[FSL_OFF + (unsigned)(b*N_+t)*384u + 2u*(unsigned)j],
                     &wsu[SL_OFF  + (unsigned)(b*N_+t)*384u + 2u*(unsigned)j],
                     sfast[j>>6], tagH);
    }
    bar_();   // B2b — ss full
  }
}

// ---------- pass 2a: G^T = (S@W1b)^T, C = Hprov@W1a + zc, NF = S@Wf + bf ----------
// reads the MALL (SL/HL) copies — wave-3-written for all t; kernel boundary = acquire.
__global__ void k_p2a(const float* __restrict__ W1, const float* __restrict__ Wf,
    const float* __restrict__ bf, float* ws, float* out)
{
  int j = blockIdx.x, b = blockIdx.y, tid = threadIdx.x;
  __shared__ float srow[H_], hrow[H_];
  __shared__ float nfp[3][F_];
  srow[tid] = ws[SL_OFF + (unsigned)(b*N_+j)*384u + 2u*tid];
  hrow[tid] = ws[HL_OFF + (unsigned)(b*N_+j)*384u + 2u*tid];   // garbage for j=0, C[0] unused
  __syncthreads();
  float accG = 0.f, accC = 0.f;
  for (int k=0;k<H_;k++){
    float sv = srow[k], hv = hrow[k];
    accG += sv * W1[(size_t)(H_+k)*H_ + tid];
    accC += hv * W1[(size_t)k*H_ + tid];
  }
  ws[G_OFF + ((size_t)b*H_ + tid)*N_ + j] = accG;    // transposed store
  ws[C_OFF + (size_t)(b*N_+j)*H_ + tid] = accC + ws[ZC_OFF + b*H_ + tid];
  int f = tid & 63, kp = tid >> 6;
  float a = 0.f;
  for (int i=0;i<64;i++){ int k = kp*64 + i; a += srow[k]*Wf[(size_t)k*F_ + f]; }
  nfp[kp][f] = a;
  __syncthreads();
  if (tid < F_) out[NF_OUT + (size_t)(b*N_+j)*F_ + tid] = nfp[0][tid]+nfp[1][tid]+nfp[2][tid] + bf[tid];
}

// ---------- pass 2b: log-likelihood, lane-per-candidate-parent ----------
__global__ void __launch_bounds__(256) k_p2b(const float* __restrict__ W2,
    const float* __restrict__ b2p, float* ws, float* out)
{
  int t = blockIdx.x + 1, b = blockIdx.y;
  int tid = threadIdx.x; int lane = tid & 63; int wv = tid >> 6;
  __shared__ float cv[H_], w2s[H_];
  __shared__ float wsum[4];
  unsigned long long* ws64 = (unsigned long long*)ws;
  if (tid < H_){
    cv[tid] = ws[C_OFF + (size_t)(b*N_+t)*H_ + tid];
    w2s[tid] = W2[tid];
  }
  __syncthreads();
  float acc = 0.f;
  if (tid < t){
    const float* GT = ws + G_OFF + (size_t)b*H_*N_;
    float a = 0.f;
    for (int k=0;k<H_;k++) a += fmaxf(cv[k] + GT[(size_t)k*N_ + tid], 0.f) * w2s[k];
    float logit = a + b2p[0];
    float pp = 1.0f/(1.0f+__expf(-logit));
    unsigned long long an = ws64[AN64 + (size_t)(b*N_+t)*4 + (tid>>6)];
    unsigned long long tg = ws64[TG64 + (size_t)(b*N_+t)*4 + (tid>>6)];
    float anc = (float)((an >> (tid&63)) & 1ULL);
    pp = pp * (1.0f - anc);
    pp = fminf(fmaxf(pp, 1e-6f), 1.0f - 1e-6f);
    int tgb = (int)((tg >> (tid&63)) & 1ULL);
    acc = tgb ? logf(pp) : log1pf(-pp);
  }
  #pragma unroll
  for (int m=32;m>=1;m>>=1) acc += __shfl_xor(acc, m);
  if (lane == 0) wsum[wv] = acc;
  __syncthreads();
  if (tid == 0) atomicAdd(out + LL_OUT, wsum[0]+wsum[1]+wsum[2]+wsum[3]);
}

extern "C" void kernel_launch(void* const* d_in, const int* in_sizes, int n_in,
                              void* d_out, int out_size, void* d_ws, size_t ws_size,
                              hipStream_t stream) {
  (void)in_sizes; (void)n_in; (void)out_size; (void)ws_size;
  const float* z     = (const float*)d_in[0];
  const float* tgt   = (const float*)d_in[1];
  const float* Winit = (const float*)d_in[2];
  const float* binit = (const float*)d_in[3];
  const float* Wih   = (const float*)d_in[4];
  const float* Whh   = (const float*)d_in[5];
  const float* bih   = (const float*)d_in[6];
  const float* bhh   = (const float*)d_in[7];
  const float* W1    = (const float*)d_in[8];
  const float* b1    = (const float*)d_in[9];
  const float* W2    = (const float*)d_in[10];
  const float* b2    = (const float*)d_in[11];
  const float* Wf    = (const float*)d_in[12];
  const float* bf    = (const float*)d_in[13];
  float* out = (float*)d_out;
  float* ws  = (float*)d_ws;

  hipMemcpyAsync(d_out, d_in[1], (size_t)B_*N_*N_*sizeof(float), hipMemcpyDeviceToDevice, stream);

  k_pre1<<<dim3(N_+1, B_), dim3(192), 0, stream>>>(z, Winit, binit, W1, b1, tgt, ws, out);
  k_pass1<<<dim3(24), dim3(512), 0, stream>>>(z, Wih, Whh, bih, bhh, ws);
  k_p2a<<<dim3(N_, B_), dim3(H_), 0, stream>>>(W1, Wf, bf, ws, out);
  k_p2b<<<dim3(N_-1, B_), dim3(256), 0, stream>>>(W2, b2, ws, out);
}

// Round 7
// 910.902 us; speedup vs baseline: 1.1735x; 1.1122x over previous
//
#include <hip/hip_runtime.h>
#include <stdint.h>

#define B_ 4
#define N_ 256
#define H_ 192
#define H3_ 576
#define F_ 64

// ---- workspace layout (32-bit words) ----
// HL/SL (MALL) and FHL/FSL (fast, XCD-L2) rows are 192 tagged u64:
// high32 = tag (t+1), low32 = fp32 bits. Tags 1..256; 0xAAAAAAAA poison never matches.
#define H0_OFF   0u
#define ZC_OFF   1024u
#define HL_OFF   2048u        // MALL h_prov rows [b][t][192] u64
#define SL_OFF   395264u      // MALL S rows
#define AN_OFF   788480u      // [b][t][4] u64 ancestor masks
#define TG_OFF   796672u      // [b][t][4] u64 target masks
#define PL_OFF   804864u      // parent lists (u8)
#define PC_OFF   870400u      // parent counts
#define DG_OFF   871424u      // 1/deg
#define D_OFF    872448u      // d-history [b][blk][node][192] f32 (own-block cols of S[node]@W_ih)
#define G_OFF    1462272u     // G^T: [b][k][N]  (post-pass only)
#define C_OFF    1658880u     // Hprov@W1a + zc  (post-pass only)
#define FHL_OFF  1855488u     // fast (XCD-L2) h_prov rows
#define FSL_OFF  2248704u     // fast (XCD-L2) S rows
#define XC_OFF   2641920u     // (unused this round)

#define AN64 (AN_OFF/2)
#define TG64 (TG_OFF/2)

#define NF_OUT 262144u
#define LL_OUT 327680u

__device__ __forceinline__ float sigm_(float x){ return 1.0f/(1.0f + __expf(-x)); }
__device__ __forceinline__ float tanh_(float x){
  float ax = fabsf(x);
  float e = __expf(-2.0f*ax);
  float t = (1.0f - e)/(1.0f + e);
  return x < 0.0f ? -t : t;
}

// MALL (agent/sc1) tagged ops — proven hang-proof publish path.
__device__ __forceinline__ void st_mall_(uint32_t* p, unsigned long long u){
  __hip_atomic_store((unsigned long long*)p, u, __ATOMIC_RELAXED, __HIP_MEMORY_SCOPE_AGENT);
}
__device__ __forceinline__ unsigned long long ld_mall_(const uint32_t* p){
  return __hip_atomic_load((const unsigned long long*)p, __ATOMIC_RELAXED, __HIP_MEMORY_SCOPE_AGENT);
}
// nt load: non-temporal => never allocates in L1. FHL/FSL lines are ONLY ever read
// via nt (and written by no-allocate stores), so they are never L1-resident and an
// nt load always observes the XCD-shared L2 (~300cy) — no buffer_inv, no stale-L1
// trap (r2 hang / r5 mirror-stall mechanism).
__device__ __forceinline__ unsigned long long ld_nt_(const uint32_t* p){
  unsigned long long v;
  asm volatile("global_load_dwordx2 %0, %1, off nt\n\t"
               "s_waitcnt vmcnt(0)"
               : "=v"(v) : "v"(p) : "memory");
  return v;
}
// dual publish: plain write-through store (own XCD L2) + sc1 store (MALL).
__device__ __forceinline__ void pub_(uint32_t* fp, uint32_t* mp, float v, uint32_t tag){
  unsigned long long u = ((unsigned long long)tag<<32) | (unsigned long long)__float_as_uint(v);
  __hip_atomic_store((unsigned long long*)fp, u, __ATOMIC_RELAXED, __HIP_MEMORY_SCOPE_WORKGROUP);
  st_mall_(mp, u);
}
// dual-spin poll: EVERY iteration checks the L2 (nt) copy first, then the MALL copy.
// Detect latency = min(L2, MALL); hang-proof by construction (MALL checked every
// iteration, and the MALL copy is always written by pub_).
__device__ __forceinline__ float pollH_(const uint32_t* fp, const uint32_t* mp, uint32_t tag){
  unsigned long long x;
  for(;;){
    x = ld_nt_(fp);
    if ((uint32_t)(x>>32) != tag){
      unsigned long long m = ld_mall_(mp);
      if ((uint32_t)(m>>32) == tag) x = m;
    }
    if (__all((int)((uint32_t)(x>>32) == tag))) break;
  }
  return __uint_as_float((uint32_t)x);
}
// raw barrier: LDS ordering only — no vmcnt drain, so the publisher's in-flight
// MALL store ack never charges the whole block at the barrier.
__device__ __forceinline__ void bar_(){
  asm volatile("s_waitcnt lgkmcnt(0)" ::: "memory");
  __builtin_amdgcn_s_barrier();
  asm volatile("" ::: "memory");
}

// ---------- pre1: (bx<N_): parent lists/bitmasks/deg | (bx==N_): h0, zc, ll=0 ----------
__global__ void __launch_bounds__(192) k_pre1(const float* __restrict__ z,
    const float* __restrict__ Winit, const float* __restrict__ binit,
    const float* __restrict__ W1, const float* __restrict__ b1,
    const float* __restrict__ tgt, float* ws, float* out)
{
  int bx = blockIdx.x, b = blockIdx.y, tid = threadIdx.x;
  if (bx == N_){
    __shared__ float zs[H_];
    zs[tid] = z[b*H_ + tid];
    __syncthreads();
    float a0=0.f, a1=0.f;
    for (int k=0;k<H_;k++){
      float zv = zs[k];
      a0 += zv * Winit[(size_t)k*H_ + tid];
      a1 += zv * W1[(size_t)(2*H_ + k)*H_ + tid];
    }
    ws[H0_OFF + b*H_ + tid] = tanh_(a0 + binit[tid]);
    ws[ZC_OFF + b*H_ + tid] = a1 + b1[tid];
    if (b==0 && tid==0) out[LL_OUT] = 0.0f;
    return;
  }
  if (tid >= 64) return;
  int t = bx, lane = tid;
  uint32_t* wsu = (uint32_t*)ws;
  unsigned long long* ws64 = (unsigned long long*)ws;
  const float* row = tgt + ((size_t)(b*N_) + t)*N_;
  uint8_t* pl = ((uint8_t*)&wsu[PL_OFF]) + (size_t)(b*N_ + t)*N_;
  int cnt = 0;
  #pragma unroll
  for (int m=0;m<4;m++){
    float v = row[m*64 + lane];
    bool p = (v != 0.0f);
    unsigned long long bw = __ballot(p);
    if (lane == 0) ws64[TG64 + (size_t)(b*N_+t)*4 + m] = bw;
    if (p){
      int pos = cnt + (int)__popcll(bw & ((1ULL<<lane)-1ULL));
      pl[pos] = (uint8_t)(m*64 + lane);
    }
    cnt += (int)__popcll(bw);
  }
  if (lane == 0){
    wsu[PC_OFF + b*N_ + t] = (uint32_t)cnt;
    ws[DG_OFF + b*N_ + t] = 1.0f / fmaxf((float)cnt, 1.0f);
  }
}

// ---------- pass 1: 3 blocks per batch, each owns 64 hidden elems (192 gate cols) ----------
// r1 schedule verbatim; only (a) dual-spin nt+MALL poll, (b) lgkm-only in-loop barriers.
__global__ void __launch_bounds__(512, 2) k_pass1(const float* __restrict__ z,
    const float* __restrict__ Wih, const float* __restrict__ Whh,
    const float* __restrict__ bih_g, const float* __restrict__ bhh_g,
    float* ws)
{
  int bx = blockIdx.x;
  int b = bx & 7;
  if (b >= B_) return;
  int blk = bx >> 3;                 // 0..2, bx = b, 8+b, 16+b
  int tid = threadIdx.x;
  const int e  = tid >> 3;           // 0..63
  const int kc = tid & 7;            // 0..7
  const int E  = blk*64 + e;         // global hidden element

  float* wsf = ws;
  uint32_t* wsu = (uint32_t*)ws;
  unsigned long long* ws64 = (unsigned long long*)ws;

  __shared__ __align__(16) float sh[H_];     // h_prov(t), full vector
  __shared__ __align__(16) float ss[H_];     // S(t), full vector
  __shared__ float sDG[N_], sTF1[N_];
  __shared__ uint32_t sPC[N_];
  __shared__ unsigned long long sAB[N_][4];  // blk0 only

  // publish S(0) ASAP (tag 1)
  {
    float v = wsf[H0_OFF + b*H_ + E];
    if (kc == 0)
      pub_(&wsu[FSL_OFF + (unsigned)(b*N_)*384u + 2u*(unsigned)E],
           &wsu[SL_OFF  + (unsigned)(b*N_)*384u + 2u*(unsigned)E], v, 1u);
    if (kc == 1) ss[E] = v;
  }

  // ---- per-step scalar tables ----
  for (int i = tid; i < N_; i += 512){
    sDG[i] = wsf[DG_OFF + b*N_ + i];
    sPC[i] = wsu[PC_OFF + b*N_ + i];
    float f1 = 0.f;
    if (i >= 1){
      unsigned long long w1 = ws64[TG64 + (size_t)(b*N_+i)*4 + ((i-1)>>6)];
      f1 = (float)((w1 >> ((i-1)&63)) & 1ULL);
    }
    sTF1[i] = f1;
  }
  if (blk == 0 && tid >= 192 && tid < 196) sAB[0][tid-192] = 0ULL;

  // ---- weights: 3 gate cols x 24-k chunk ----
  float rwih[3][24], rwhh[3][24], rbih[3], rbhh[3], rghz[3];
  #pragma unroll
  for (int g=0; g<3; g++){
    int col = g*H_ + E;
    #pragma unroll
    for (int i=0;i<24;i++){
      rwih[g][i] = Wih[(size_t)(kc*24+i)*H3_ + col];
      rwhh[g][i] = Whh[(size_t)(kc*24+i)*H3_ + col];
    }
    rbih[g] = bih_g[col];
    rbhh[g] = bhh_g[col];
  }
  {
    // ghz = z@W_hh + b_hh (const across steps)
    float a0=0.f,a1=0.f,a2=0.f;
    #pragma unroll
    for (int i=0;i<24;i++){
      float zv = z[b*H_ + kc*24 + i];
      a0 += zv*rwhh[0][i]; a1 += zv*rwhh[1][i]; a2 += zv*rwhh[2][i];
    }
    #pragma unroll
    for (int m=1;m<8;m<<=1){
      a0 += __shfl_xor(a0,m); a1 += __shfl_xor(a1,m); a2 += __shfl_xor(a2,m);
    }
    rghz[0]=a0+rbhh[0]; rghz[1]=a1+rbhh[1]; rghz[2]=a2+rbhh[2];
  }
  float zreg = z[b*H_ + E];

  __syncthreads();   // full drain once: S(0) dual-publish committed
  // poll foreign S(0) into LDS
  if (tid < 128){
    int j = (tid < blk*64) ? tid : tid + 64;
    ss[j] = pollH_(&wsu[FSL_OFF + (unsigned)(b*N_)*384u + 2u*(unsigned)j],
                   &wsu[SL_OFF  + (unsigned)(b*N_)*384u + 2u*(unsigned)j], 1u);
  }
  __syncthreads();

  float q0=0.f, q1=0.f, q2=0.f;
  const uint8_t* plbase = ((const uint8_t*)&wsu[PL_OFF]) + (size_t)(b*N_)*N_;
  float* Dbase = wsf + D_OFF + (size_t)((b*3+blk)*N_)*H_;

  for (int t=1; t<N_; t++){
    const uint32_t tagH = (uint32_t)(t+1);
    // ---- mv1: d = S(t-1) @ W_ih (own 3 cols, k-chunk), butterfly over kc ----
    float d0=0.f,d1=0.f,d2=0.f;
    #pragma unroll
    for (int c=0;c<6;c++){
      float4 v4 = *(const float4*)&ss[kc*24 + c*4];
      float xx0=v4.x, xx1=v4.y, xx2=v4.z, xx3=v4.w;
      d0 += xx0*rwih[0][c*4+0]; d1 += xx0*rwih[1][c*4+0]; d2 += xx0*rwih[2][c*4+0];
      d0 += xx1*rwih[0][c*4+1]; d1 += xx1*rwih[1][c*4+1]; d2 += xx1*rwih[2][c*4+1];
      d0 += xx2*rwih[0][c*4+2]; d1 += xx2*rwih[1][c*4+2]; d2 += xx2*rwih[2][c*4+2];
      d0 += xx3*rwih[0][c*4+3]; d1 += xx3*rwih[1][c*4+3]; d2 += xx3*rwih[2][c*4+3];
    }
    #pragma unroll
    for (int m=1;m<8;m<<=1){
      d0 += __shfl_xor(d0,m); d1 += __shfl_xor(d1,m); d2 += __shfl_xor(d2,m);
    }
    q0 += d0; q1 += d1; q2 += d2;
    float invt = 1.0f/(float)t;
    // ---- gates1: h_prov ----
    float r = sigm_(q0*invt + rbih[0] + rghz[0]);
    float u = sigm_(q1*invt + rbih[1] + rghz[1]);
    float n = tanh_(q2*invt + rbih[2] + r*rghz[2]);
    float hp = (1.0f-u)*n + u*zreg;
    // publish h_prov + store own d row (node t-1)
    if (kc == 0){
      pub_(&wsu[FHL_OFF + (unsigned)(b*N_+t)*384u + 2u*(unsigned)E],
           &wsu[HL_OFF  + (unsigned)(b*N_+t)*384u + 2u*(unsigned)E], hp, tagH);
      float* Dr = Dbase + (size_t)(t-1)*H_;
      Dr[e] = d0; Dr[64+e] = d1; Dr[128+e] = d2;
    }
    if (kc == 1) sh[E] = hp;
    // ---- gather parent d (p <= t-2; p==t-1 handled via tf1*d in-reg) ----
    float ga0=0.f, ga1=0.f, ga2=0.f;
    {
      int pc = (int)sPC[t];
      const uint8_t* pl = plbase + (size_t)t*N_;
      for (int i=kc; i<pc; i+=8){
        int p = pl[i];
        if (p == t-1) continue;
        const float* Dp = Dbase + (size_t)p*H_;
        ga0 += Dp[e]; ga1 += Dp[64+e]; ga2 += Dp[128+e];
      }
    }
    #pragma unroll
    for (int m=1;m<8;m<<=1){
      ga0 += __shfl_xor(ga0,m); ga1 += __shfl_xor(ga1,m); ga2 += __shfl_xor(ga2,m);
    }
    // ---- phase-1 exchange: poll foreign h_prov; blk0 wave3 does ancestor row ----
    if (tid < 128){
      int j = (tid < blk*64) ? tid : tid + 64;
      sh[j] = pollH_(&wsu[FHL_OFF + (unsigned)(b*N_+t)*384u + 2u*(unsigned)j],
                     &wsu[HL_OFF  + (unsigned)(b*N_+t)*384u + 2u*(unsigned)j], tagH);
    } else if (blk == 0 && tid >= 192 && tid < 208){
      int lane16 = tid - 192;
      int ip = lane16 >> 2, w = lane16 & 3;
      int pc = (int)sPC[t];
      const uint8_t* pl = plbase + (size_t)t*N_;
      unsigned long long acc = 0ULL;
      for (int i=ip; i<pc; i+=4) acc |= sAB[pl[i]][w];
      acc |= __shfl_xor(acc, 4);
      acc |= __shfl_xor(acc, 8);
      if (ip == 0){
        ws64[AN64 + (size_t)(b*N_+t)*4 + w] = acc;
        sAB[t][w] = acc | ws64[TG64 + (size_t)(b*N_+t)*4 + w];
      }
    }
    bar_();   // B1 (lgkm only)
    // ---- mv2: gh2 = h_prov @ W_hh ----
    float y0=0.f,y1=0.f,y2=0.f;
    #pragma unroll
    for (int c=0;c<6;c++){
      float4 v4 = *(const float4*)&sh[kc*24 + c*4];
      float xx0=v4.x, xx1=v4.y, xx2=v4.z, xx3=v4.w;
      y0 += xx0*rwhh[0][c*4+0]; y1 += xx0*rwhh[1][c*4+0]; y2 += xx0*rwhh[2][c*4+0];
      y0 += xx1*rwhh[0][c*4+1]; y1 += xx1*rwhh[1][c*4+1]; y2 += xx1*rwhh[2][c*4+1];
      y0 += xx2*rwhh[0][c*4+2]; y1 += xx2*rwhh[1][c*4+2]; y2 += xx2*rwhh[2][c*4+2];
      y0 += xx3*rwhh[0][c*4+3]; y1 += xx3*rwhh[1][c*4+3]; y2 += xx3*rwhh[2][c*4+3];
    }
    #pragma unroll
    for (int m=1;m<8;m<<=1){
      y0 += __shfl_xor(y0,m); y1 += __shfl_xor(y1,m); y2 += __shfl_xor(y2,m);
    }
    // ---- gates2: S(t) ----
    float dginv = sDG[t], tf1 = sTF1[t];
    float gxa = (ga0 + tf1*d0)*dginv + rbih[0];
    float gxb = (ga1 + tf1*d1)*dginv + rbih[1];
    float gxc = (ga2 + tf1*d2)*dginv + rbih[2];
    float r2 = sigm_(gxa + y0 + rbhh[0]);
    float u2 = sigm_(gxb + y1 + rbhh[1]);
    float n2 = tanh_(gxc + r2*(y2 + rbhh[2]));
    float hn = (1.0f-u2)*n2 + u2*hp;
    if (kc == 0)
      pub_(&wsu[FSL_OFF + (unsigned)(b*N_+t)*384u + 2u*(unsigned)E],
           &wsu[SL_OFF  + (unsigned)(b*N_+t)*384u + 2u*(unsigned)E], hn, tagH);
    if (kc == 1) ss[E] = hn;
    // ---- phase-2 exchange: poll foreign S(t) ----
    if (tid < 128){
      int j = (tid < blk*64) ? tid : tid + 64;
      ss[j] = pollH_(&wsu[FSL_OFF + (unsigned)(b*N_+t)*384u + 2u*(unsigned)j],
                     &wsu[SL_OFF  + (unsigned)(b*N_+t)*384u + 2u*(unsigned)j], tagH);
    }
    bar_();   // B2 (lgkm only)
  }
}

// ---------- pass 2a: G^T = (S@W1b)^T, C = Hprov@W1a + zc, NF = S@Wf + bf ----------
__global__ void k_p2a(const float* __restrict__ W1, const float* __restrict__ Wf,
    const float* __restrict__ bf, float* ws, float* out)
{
  int j = blockIdx.x, b = blockIdx.y, tid = threadIdx.x;
  __shared__ float srow[H_], hrow[H_];
  __shared__ float nfp[3][F_];
  srow[tid] = ws[SL_OFF + (unsigned)(b*N_+j)*384u + 2u*tid];
  hrow[tid] = ws[HL_OFF + (unsigned)(b*N_+j)*384u + 2u*tid];   // garbage for j=0, C[0] unused
  __syncthreads();
  float accG = 0.f, accC = 0.f;
  for (int k=0;k<H_;k++){
    float sv = srow[k], hv = hrow[k];
    accG += sv * W1[(size_t)(H_+k)*H_ + tid];
    accC += hv * W1[(size_t)k*H_ + tid];
  }
  ws[G_OFF + ((size_t)b*H_ + tid)*N_ + j] = accG;    // transposed store
  ws[C_OFF + (size_t)(b*N_+j)*H_ + tid] = accC + ws[ZC_OFF + b*H_ + tid];
  int f = tid & 63, kp = tid >> 6;
  float a = 0.f;
  for (int i=0;i<64;i++){ int k = kp*64 + i; a += srow[k]*Wf[(size_t)k*F_ + f]; }
  nfp[kp][f] = a;
  __syncthreads();
  if (tid < F_) out[NF_OUT + (size_t)(b*N_+j)*F_ + tid] = nfp[0][tid]+nfp[1][tid]+nfp[2][tid] + bf[tid];
}

// ---------- pass 2b: log-likelihood, lane-per-candidate-parent ----------
__global__ void __launch_bounds__(256) k_p2b(const float* __restrict__ W2,
    const float* __restrict__ b2p, float* ws, float* out)
{
  int t = blockIdx.x + 1, b = blockIdx.y;
  int tid = threadIdx.x; int lane = tid & 63; int wv = tid >> 6;
  __shared__ float cv[H_], w2s[H_];
  __shared__ float wsum[4];
  unsigned long long* ws64 = (unsigned long long*)ws;
  if (tid < H_){
    cv[tid] = ws[C_OFF + (size_t)(b*N_+t)*H_ + tid];
    w2s[tid] = W2[tid];
  }
  __syncthreads();
  float acc = 0.f;
  if (tid < t){
    const float* GT = ws + G_OFF + (size_t)b*H_*N_;
    float a = 0.f;
    for (int k=0;k<H_;k++) a += fmaxf(cv[k] + GT[(size_t)k*N_ + tid], 0.f) * w2s[k];
    float logit = a + b2p[0];
    float pp = 1.0f/(1.0f+__expf(-logit));
    unsigned long long an = ws64[AN64 + (size_t)(b*N_+t)*4 + (tid>>6)];
    unsigned long long tg = ws64[TG64 + (size_t)(b*N_+t)*4 + (tid>>6)];
    float anc = (float)((an >> (tid&63)) & 1ULL);
    pp = pp * (1.0f - anc);
    pp = fminf(fmaxf(pp, 1e-6f), 1.0f - 1e-6f);
    int tgb = (int)((tg >> (tid&63)) & 1ULL);
    acc = tgb ? logf(pp) : log1pf(-pp);
  }
  #pragma unroll
  for (int m=32;m>=1;m>>=1) acc += __shfl_xor(acc, m);
  if (lane == 0) wsum[wv] = acc;
  __syncthreads();
  if (tid == 0) atomicAdd(out + LL_OUT, wsum[0]+wsum[1]+wsum[2]+wsum[3]);
}

extern "C" void kernel_launch(void* const* d_in, const int* in_sizes, int n_in,
                              void* d_out, int out_size, void* d_ws, size_t ws_size,
                              hipStream_t stream) {
  (void)in_sizes; (void)n_in; (void)out_size; (void)ws_size;
  const float* z     = (const float*)d_in[0];
  const float* tgt   = (const float*)d_in[1];
  const float* Winit = (const float*)d_in[2];
  const float* binit = (const float*)d_in[3];
  const float* Wih   = (const float*)d_in[4];
  const float* Whh   = (const float*)d_in[5];
  const float* bih   = (const float*)d_in[6];
  const float* bhh   = (const float*)d_in[7];
  const float* W1    = (const float*)d_in[8];
  const float* b1    = (const float*)d_in[9];
  const float* W2    = (const float*)d_in[10];
  const float* b2    = (const float*)d_in[11];
  const float* Wf    = (const float*)d_in[12];
  const float* bf    = (const float*)d_in[13];
  float* out = (float*)d_out;
  float* ws  = (float*)d_ws;

  hipMemcpyAsync(d_out, d_in[1], (size_t)B_*N_*N_*sizeof(float), hipMemcpyDeviceToDevice, stream);

  k_pre1<<<dim3(N_+1, B_), dim3(192), 0, stream>>>(z, Winit, binit, W1, b1, tgt, ws, out);
  k_pass1<<<dim3(24), dim3(512), 0, stream>>>(z, Wih, Whh, bih, bhh, ws);
  k_p2a<<<dim3(N_, B_), dim3(H_), 0, stream>>>(W1, Wf, bf, ws, out);
  k_p2b<<<dim3(N_-1, B_), dim3(256), 0, stream>>>(W2, b2, ws, out);
}